// Round 5
// baseline (324.757 us; speedup 1.0000x reference)
//
#include <hip/hip_runtime.h>

// Sinkhorn on 8192 independent 64x64 matrices — scaling-vector (u,v) form.
//   A0 = exp2(t - rowmax(t)),  t = gp + noise*10*log2e,  gp = 10*log2(1+2^(-g*log2e))
//   iterate: u = 1/(A0 v), v = 1/(A0^T u);  out = diag(u) A0 diag(v)
// One wave per matrix; lane (lr,lc) owns the 8x8 tile rows lr*8.., cols lc*8.. .
// R5: (a) inline-asm v_pk_fma_f32 for all dot FMAs (plain-VALU asm is hazard-
// safe; only DPP asm raced in R2), (b) __launch_bounds__(256,4) caps the
// unified reg budget at 128 so the matrix lives in arch VGPRs (R4: VGPR=72 +
// hidden AGPR split at occupancy 28%). Cross-lane stays on proven builtins.

typedef float v2f __attribute__((ext_vector_type(2)));

#define L2E   1.4426950408889634f
#define SCALE 14.426950408889634f   // 10 * log2(e)
#define NITER 50

__device__ __forceinline__ v2f pk_fma(v2f a, v2f b, v2f c) {
  v2f d;
  asm("v_pk_fma_f32 %0, %1, %2, %3" : "=v"(d) : "v"(a), "v"(b), "v"(c));
  return d;
}
__device__ __forceinline__ v2f pk_mul(v2f a, v2f b) {
  v2f d;
  asm("v_pk_mul_f32 %0, %1, %2" : "=v"(d) : "v"(a), "v"(b));
  return d;
}

template<int CTRL>
__device__ __forceinline__ float dppmov(float x) {
  return __int_as_float(__builtin_amdgcn_update_dpp(
      0, __float_as_int(x), CTRL, 0xF, 0xF, true));
}
// xor1: quad_perm [1,0,3,2] = 0xB1 ; xor2: quad_perm [2,3,0,1] = 0x4E
// xor7: row_half_mirror = 0x141    ; xor8: row_ror:8 = 0x128

__device__ __forceinline__ float swz_x16(float x) {  // value from lane^16 (within 32)
  return __int_as_float(__builtin_amdgcn_ds_swizzle(__float_as_int(x), 0x401F));
}
__device__ __forceinline__ float bperm(int addr, float x) {
  return __int_as_float(__builtin_amdgcn_ds_bpermute(addr, __float_as_int(x)));
}

// gp = 10*log2(1 + 2^(-g*log2e))  (== softplus(-g)/temp in base-2 domain), 4096 elems
__global__ __launch_bounds__(256) void prep_gp(const float* __restrict__ g,
                                               float* __restrict__ gp) {
  const int i = blockIdx.x * 256 + threadIdx.x;
  const float x = g[i];
  gp[i] = 10.0f * __builtin_amdgcn_logf(1.0f + __builtin_amdgcn_exp2f(-x * L2E));
}

__global__ __launch_bounds__(256, 4) void sinkhorn64(
    const float* __restrict__ gp,      // may be null -> compute from gamma
    const float* __restrict__ gamma,
    const float* __restrict__ noise,
    float* __restrict__ out, int batch) {
  const int lane = threadIdx.x & 63;
  const int m = blockIdx.x * 4 + (threadIdx.x >> 6);
  if (m >= batch) return;

  const int lr = lane >> 3;
  const int lc = lane & 7;
  const int tile_off = (lr * 8) * 64 + lc * 8;
  const float* src = noise + (size_t)m * 4096 + tile_off;
  const int addr32 = (lane ^ 32) << 2;

  v2f a2[8][4];   // a2[i][jj] = (A[row i][col 2jj], A[row i][col 2jj+1]) of 8x8 tile

  // ---- init: t = gp + noise*SCALE ----
#pragma unroll
  for (int i = 0; i < 8; ++i) {
    const float4 n0 = *(const float4*)(src + i * 64);
    const float4 n1 = *(const float4*)(src + i * 64 + 4);
    const v2f n2[4] = {{n0.x, n0.y}, {n0.z, n0.w}, {n1.x, n1.y}, {n1.z, n1.w}};
    v2f g2[4];
    if (gp) {
      const float4 g0 = *(const float4*)(gp + tile_off + i * 64);
      const float4 g1 = *(const float4*)(gp + tile_off + i * 64 + 4);
      g2[0] = (v2f){g0.x, g0.y}; g2[1] = (v2f){g0.z, g0.w};
      g2[2] = (v2f){g1.x, g1.y}; g2[3] = (v2f){g1.z, g1.w};
    } else {
      const float4 g0 = *(const float4*)(gamma + tile_off + i * 64);
      const float4 g1 = *(const float4*)(gamma + tile_off + i * 64 + 4);
      const float gv[8] = {g0.x, g0.y, g0.z, g0.w, g1.x, g1.y, g1.z, g1.w};
      float gq[8];
#pragma unroll
      for (int j = 0; j < 8; ++j)
        gq[j] = 10.0f * __builtin_amdgcn_logf(1.0f + __builtin_amdgcn_exp2f(-gv[j] * L2E));
      g2[0] = (v2f){gq[0], gq[1]}; g2[1] = (v2f){gq[2], gq[3]};
      g2[2] = (v2f){gq[4], gq[5]}; g2[3] = (v2f){gq[6], gq[7]};
    }
    const v2f sc2 = {SCALE, SCALE};
#pragma unroll
    for (int jj = 0; jj < 4; ++jj)
      a2[i][jj] = pk_fma(n2[jj], sc2, g2[jj]);
  }

  // ---- rowmax subtraction + exp2 ----
#pragma unroll
  for (int i = 0; i < 8; ++i) {
    v2f m2 = __builtin_elementwise_max(
        __builtin_elementwise_max(a2[i][0], a2[i][1]),
        __builtin_elementwise_max(a2[i][2], a2[i][3]));
    float mx = fmaxf(m2.x, m2.y);
    mx = fmaxf(mx, dppmov<0xB1>(mx));
    mx = fmaxf(mx, dppmov<0x4E>(mx));
    mx = fmaxf(mx, dppmov<0x141>(mx));
    const v2f mx2 = {mx, mx};
#pragma unroll
    for (int jj = 0; jj < 4; ++jj) {
      const v2f d = a2[i][jj] - mx2;
      a2[i][jj] = (v2f){__builtin_amdgcn_exp2f(d.x), __builtin_amdgcn_exp2f(d.y)};
    }
  }

  // ---- scaling-vector Sinkhorn ----
  v2f vv[4];
#pragma unroll
  for (int jj = 0; jj < 4; ++jj) vv[jj] = (v2f){1.0f, 1.0f};
  float u[8];

#pragma unroll 1
  for (int it = 0; it < NITER; ++it) {
    // row phase: u[i] = 1/sum_c A[i][c] v[c]
#pragma unroll
    for (int i = 0; i < 8; ++i) {
      v2f s2 = pk_mul(a2[i][0], vv[0]);
      s2 = pk_fma(a2[i][1], vv[1], s2);
      s2 = pk_fma(a2[i][2], vv[2], s2);
      s2 = pk_fma(a2[i][3], vv[3], s2);
      float s = s2.x + s2.y;
      s += dppmov<0xB1>(s);
      s += dppmov<0x4E>(s);
      s += dppmov<0x141>(s);
      u[i] = __builtin_amdgcn_rcpf(s);
    }
    // col phase: v[j] = 1/sum_r A[r][j] u[r]
    v2f ub[8];
#pragma unroll
    for (int i = 0; i < 8; ++i) ub[i] = (v2f){u[i], u[i]};
#pragma unroll
    for (int jj = 0; jj < 4; ++jj) {
      v2f s2 = pk_mul(a2[0][jj], ub[0]);
#pragma unroll
      for (int i = 1; i < 8; ++i) s2 = pk_fma(a2[i][jj], ub[i], s2);
      float sx = s2.x, sy = s2.y;
      sx += dppmov<0x128>(sx);
      sx += swz_x16(sx);
      sx += bperm(addr32, sx);
      sy += dppmov<0x128>(sy);
      sy += swz_x16(sy);
      sy += bperm(addr32, sy);
      vv[jj] = (v2f){__builtin_amdgcn_rcpf(sx), __builtin_amdgcn_rcpf(sy)};
    }
  }

  // ---- epilogue: out = diag(u) A0 diag(v) ----
  float* dst = out + (size_t)m * 4096 + tile_off;
#pragma unroll
  for (int i = 0; i < 8; ++i) {
    const v2f ui2 = (v2f){u[i], u[i]};
    v2f o2[4];
#pragma unroll
    for (int jj = 0; jj < 4; ++jj) o2[jj] = pk_mul(pk_mul(a2[i][jj], ui2), vv[jj]);
    *(float4*)(dst + i * 64)     = make_float4(o2[0].x, o2[0].y, o2[1].x, o2[1].y);
    *(float4*)(dst + i * 64 + 4) = make_float4(o2[2].x, o2[2].y, o2[3].x, o2[3].y);
  }
}

extern "C" void kernel_launch(void* const* d_in, const int* in_sizes, int n_in,
                              void* d_out, int out_size, void* d_ws, size_t ws_size,
                              hipStream_t stream) {
  const float* gamma = (const float*)d_in[0];
  const float* noise = (const float*)d_in[1];
  float* out = (float*)d_out;
  const int batch = in_sizes[1] / 4096;      // 8192
  const int blocks = (batch + 3) / 4;

  float* gp = nullptr;
  if (ws_size >= 4096 * sizeof(float)) {
    gp = (float*)d_ws;
    prep_gp<<<16, 256, 0, stream>>>(gamma, gp);
  }
  sinkhorn64<<<blocks, 256, 0, stream>>>(gp, gamma, noise, out, batch);
}

// Round 6
// 309.825 us; speedup vs baseline: 1.0482x; 1.0482x over previous
//
#include <hip/hip_runtime.h>

// Sinkhorn on 8192 independent 64x64 matrices — scaling-vector (u,v) form.
//   A0 = exp2(t - rowmax(t)),  t = gp + noise*10*log2e,  gp = 10*log2(1+2^(-g*log2e))
//   iterate: u = 1/(A0 v), v = 1/(A0^T u);  out = diag(u) A0 diag(v)
// One wave per matrix; lane (lr,lc) owns the 8x8 tile rows lr*8.., cols lc*8.. .
// R6: amdgpu_waves_per_eu(3,3) pins the allocator's occupancy target so the
// 64-float/lane matrix lives in ARCH VGPRs. R1/R4/R5 all showed VGPR_Count
// 52-72 (< live state) => compiler was spilling the matrix to AGPRs to chase
// 8 waves/EU, paying ~128 v_accvgpr_read/write per iteration in the hot loop.
// Body identical to R4 (best: 170us). Cross-lane via proven hazard-safe
// builtins (raw asm DPP raced in R2 — never again).

typedef float v2f __attribute__((ext_vector_type(2)));

#define L2E   1.4426950408889634f
#define SCALE 14.426950408889634f   // 10 * log2(e)
#define NITER 50

template<int CTRL>
__device__ __forceinline__ float dppmov(float x) {
  return __int_as_float(__builtin_amdgcn_update_dpp(
      0, __float_as_int(x), CTRL, 0xF, 0xF, true));
}
// xor1: quad_perm [1,0,3,2] = 0xB1 ; xor2: quad_perm [2,3,0,1] = 0x4E
// xor7: row_half_mirror = 0x141    ; xor8: row_ror:8 = 0x128

__device__ __forceinline__ float swz_x16(float x) {  // value from lane^16 (within 32)
  return __int_as_float(__builtin_amdgcn_ds_swizzle(__float_as_int(x), 0x401F));
}
__device__ __forceinline__ float bperm(int addr, float x) {
  return __int_as_float(__builtin_amdgcn_ds_bpermute(addr, __float_as_int(x)));
}

// gp = 10*log2(1 + 2^(-g*log2e))  (== softplus(-g)/temp in base-2 domain), 4096 elems
__global__ __launch_bounds__(256) void prep_gp(const float* __restrict__ g,
                                               float* __restrict__ gp) {
  const int i = blockIdx.x * 256 + threadIdx.x;
  const float x = g[i];
  gp[i] = 10.0f * __builtin_amdgcn_logf(1.0f + __builtin_amdgcn_exp2f(-x * L2E));
}

__global__
__attribute__((amdgpu_flat_work_group_size(256, 256), amdgpu_waves_per_eu(3, 3)))
void sinkhorn64(
    const float* __restrict__ gp,      // may be null -> compute from gamma
    const float* __restrict__ gamma,
    const float* __restrict__ noise,
    float* __restrict__ out, int batch) {
  const int lane = threadIdx.x & 63;
  const int m = blockIdx.x * 4 + (threadIdx.x >> 6);
  if (m >= batch) return;

  const int lr = lane >> 3;
  const int lc = lane & 7;
  const int tile_off = (lr * 8) * 64 + lc * 8;
  const float* src = noise + (size_t)m * 4096 + tile_off;
  const int addr32 = (lane ^ 32) << 2;

  v2f a2[8][4];   // a2[i][jj] = (A[row i][col 2jj], A[row i][col 2jj+1]) of 8x8 tile

  // ---- init: t = gp + noise*SCALE ----
#pragma unroll
  for (int i = 0; i < 8; ++i) {
    const float4 n0 = *(const float4*)(src + i * 64);
    const float4 n1 = *(const float4*)(src + i * 64 + 4);
    const v2f n2[4] = {{n0.x, n0.y}, {n0.z, n0.w}, {n1.x, n1.y}, {n1.z, n1.w}};
    v2f g2[4];
    if (gp) {
      const float4 g0 = *(const float4*)(gp + tile_off + i * 64);
      const float4 g1 = *(const float4*)(gp + tile_off + i * 64 + 4);
      g2[0] = (v2f){g0.x, g0.y}; g2[1] = (v2f){g0.z, g0.w};
      g2[2] = (v2f){g1.x, g1.y}; g2[3] = (v2f){g1.z, g1.w};
    } else {
      const float4 g0 = *(const float4*)(gamma + tile_off + i * 64);
      const float4 g1 = *(const float4*)(gamma + tile_off + i * 64 + 4);
      const float gv[8] = {g0.x, g0.y, g0.z, g0.w, g1.x, g1.y, g1.z, g1.w};
      float gq[8];
#pragma unroll
      for (int j = 0; j < 8; ++j)
        gq[j] = 10.0f * __builtin_amdgcn_logf(1.0f + __builtin_amdgcn_exp2f(-gv[j] * L2E));
      g2[0] = (v2f){gq[0], gq[1]}; g2[1] = (v2f){gq[2], gq[3]};
      g2[2] = (v2f){gq[4], gq[5]}; g2[3] = (v2f){gq[6], gq[7]};
    }
    const v2f sc2 = {SCALE, SCALE};
#pragma unroll
    for (int jj = 0; jj < 4; ++jj)
      a2[i][jj] = __builtin_elementwise_fma(n2[jj], sc2, g2[jj]);
  }

  // ---- rowmax subtraction + exp2 ----
#pragma unroll
  for (int i = 0; i < 8; ++i) {
    v2f m2 = __builtin_elementwise_max(
        __builtin_elementwise_max(a2[i][0], a2[i][1]),
        __builtin_elementwise_max(a2[i][2], a2[i][3]));
    float mx = fmaxf(m2.x, m2.y);
    mx = fmaxf(mx, dppmov<0xB1>(mx));
    mx = fmaxf(mx, dppmov<0x4E>(mx));
    mx = fmaxf(mx, dppmov<0x141>(mx));
    const v2f mx2 = {mx, mx};
#pragma unroll
    for (int jj = 0; jj < 4; ++jj) {
      const v2f d = a2[i][jj] - mx2;
      a2[i][jj] = (v2f){__builtin_amdgcn_exp2f(d.x), __builtin_amdgcn_exp2f(d.y)};
    }
  }

  // ---- scaling-vector Sinkhorn ----
  v2f vv[4];
#pragma unroll
  for (int jj = 0; jj < 4; ++jj) vv[jj] = (v2f){1.0f, 1.0f};
  float u[8];

#pragma unroll 1
  for (int it = 0; it < NITER; ++it) {
    // row phase: u[i] = 1/sum_c A[i][c] v[c]
#pragma unroll
    for (int i = 0; i < 8; ++i) {
      v2f s2 = a2[i][0] * vv[0];
      s2 = __builtin_elementwise_fma(a2[i][1], vv[1], s2);
      s2 = __builtin_elementwise_fma(a2[i][2], vv[2], s2);
      s2 = __builtin_elementwise_fma(a2[i][3], vv[3], s2);
      float s = s2.x + s2.y;
      s += dppmov<0xB1>(s);
      s += dppmov<0x4E>(s);
      s += dppmov<0x141>(s);
      u[i] = __builtin_amdgcn_rcpf(s);
    }
    // col phase: v[j] = 1/sum_r A[r][j] u[r]
    v2f ub[8];
#pragma unroll
    for (int i = 0; i < 8; ++i) ub[i] = (v2f){u[i], u[i]};
#pragma unroll
    for (int jj = 0; jj < 4; ++jj) {
      v2f s2 = a2[0][jj] * ub[0];
#pragma unroll
      for (int i = 1; i < 8; ++i) s2 = __builtin_elementwise_fma(a2[i][jj], ub[i], s2);
      float sx = s2.x, sy = s2.y;
      sx += dppmov<0x128>(sx);
      sx += swz_x16(sx);
      sx += bperm(addr32, sx);
      sy += dppmov<0x128>(sy);
      sy += swz_x16(sy);
      sy += bperm(addr32, sy);
      vv[jj] = (v2f){__builtin_amdgcn_rcpf(sx), __builtin_amdgcn_rcpf(sy)};
    }
  }

  // ---- epilogue: out = diag(u) A0 diag(v) ----
  float* dst = out + (size_t)m * 4096 + tile_off;
#pragma unroll
  for (int i = 0; i < 8; ++i) {
    const v2f ui2 = (v2f){u[i], u[i]};
    v2f o2[4];
#pragma unroll
    for (int jj = 0; jj < 4; ++jj) o2[jj] = a2[i][jj] * ui2 * vv[jj];
    *(float4*)(dst + i * 64)     = make_float4(o2[0].x, o2[0].y, o2[1].x, o2[1].y);
    *(float4*)(dst + i * 64 + 4) = make_float4(o2[2].x, o2[2].y, o2[3].x, o2[3].y);
  }
}

extern "C" void kernel_launch(void* const* d_in, const int* in_sizes, int n_in,
                              void* d_out, int out_size, void* d_ws, size_t ws_size,
                              hipStream_t stream) {
  const float* gamma = (const float*)d_in[0];
  const float* noise = (const float*)d_in[1];
  float* out = (float*)d_out;
  const int batch = in_sizes[1] / 4096;      // 8192
  const int blocks = (batch + 3) / 4;

  float* gp = nullptr;
  if (ws_size >= 4096 * sizeof(float)) {
    gp = (float*)d_ws;
    prep_gp<<<16, 256, 0, stream>>>(gamma, gp);
  }
  sinkhorn64<<<blocks, 256, 0, stream>>>(gp, gamma, noise, out, batch);
}